// Round 12
// baseline (501.090 us; speedup 1.0000x reference)
//
#include <hip/hip_runtime.h>
#include <cmath>

#define L_SEQ 2048
#define BATCH 8
#define CIN 256
#define DIN 512
#define M_ROWS (BATCH * L_SEQ)  // 16384
#define NC 64                   // scan chunks
#define LC 32                   // chunk length

typedef __attribute__((ext_vector_type(8))) short short8;
typedef __attribute__((ext_vector_type(4))) unsigned short ushort4v;
typedef __attribute__((ext_vector_type(4))) float float4v;
typedef unsigned short u16;
typedef unsigned int u32;

__device__ inline u16 f2bf_rn(float x) {
  union { float f; unsigned u; } v;
  v.f = x;
  unsigned r = v.u + 0x7FFF + ((v.u >> 16) & 1);
  return (u16)(r >> 16);
}
__device__ inline float bf2f(u16 h) {
  union { unsigned u; float f; } v;
  v.u = ((unsigned)h) << 16;
  return v.f;
}

// async 16B global->LDS (gfx950). LDS dest = wave-uniform base + lane*16.
__device__ inline void gl_lds16(const u16* g, u16* l) {
  __builtin_amdgcn_global_load_lds(
      (const __attribute__((address_space(1))) unsigned int*)(const void*)g,
      (__attribute__((address_space(3))) unsigned int*)(void*)l, 16, 0, 0);
}

// ---------------- transpose (B,C,L) -> (B,L,C), hi/lo bf16 planes ----------------
__global__ __launch_bounds__(256) void transpose_in(const float* __restrict__ in,
                                                    u16* __restrict__ xh, u16* __restrict__ xl) {
  __shared__ float tile[32][33];
  int b = blockIdx.z;
  int l0 = blockIdx.x * 32, c0 = blockIdx.y * 32;
  int tx = threadIdx.x, ty = threadIdx.y;  // 32 x 8
#pragma unroll
  for (int k = 0; k < 4; ++k)
    tile[ty + k * 8][tx] = in[(long)(b * CIN + c0 + ty + k * 8) * L_SEQ + l0 + tx];
  __syncthreads();
#pragma unroll
  for (int k = 0; k < 4; ++k) {
    float v = tile[tx][ty + k * 8];
    long o = (long)(b * L_SEQ + l0 + ty + k * 8) * CIN + c0 + tx;
    u16 h = f2bf_rn(v);
    xh[o] = h;
    xl[o] = f2bf_rn(v - bf2f(h));
  }
}

// ---------------- weight packing to planes ----------------
__global__ __launch_bounds__(256) void split_pack(const float* __restrict__ in,
                                                  u16* __restrict__ oh, u16* __restrict__ ol,
                                                  int n) {
  int i = blockIdx.x * 256 + threadIdx.x;
  if (i < n) {
    float v = in[i];
    u16 h = f2bf_rn(v);
    oh[i] = h;
    ol[i] = f2bf_rn(v - bf2f(h));
  }
}

// Wd (640 x 512): rows 0..511 = dt_proj_w @ x_proj_w[0:16]; 512..543 = B,C rows; 544..639 = 0
__global__ __launch_bounds__(256) void build_wd(const float* __restrict__ xpw,
                                                const float* __restrict__ dtw,
                                                u16* __restrict__ Wh, u16* __restrict__ Wl) {
  int k = blockIdx.x * 256 + threadIdx.x;  // 0..511
  int n = blockIdx.y;                      // 0..639
  float v;
  if (n < 512) {
    v = 0.f;
#pragma unroll
    for (int r = 0; r < 16; ++r) v += dtw[n * 16 + r] * xpw[r * 512 + k];
  } else if (n < 544) {
    v = xpw[(16 + n - 512) * 512 + k];
  } else {
    v = 0.f;
  }
  u16 h = f2bf_rn(v);
  Wh[(long)n * 512 + k] = h;
  Wl[(long)n * 512 + k] = f2bf_rn(v - bf2f(h));
}

// W_comb (512 x 512): out_lin_w (512x256) @ out_proj_w[layer1] (256x512)
__global__ __launch_bounds__(256) void build_wcomb(const float* __restrict__ olw,
                                                   const float* __restrict__ opw,
                                                   u16* __restrict__ Wh, u16* __restrict__ Wl) {
  int d = blockIdx.x * 256 + threadIdx.x;  // 0..511
  int o = blockIdx.y;                      // 0..511
  float v = 0.f;
#pragma unroll 4
  for (int c = 0; c < 256; ++c) v += olw[o * 256 + c] * opw[(long)c * 512 + d];
  u16 h = f2bf_rn(v);
  Wh[(long)o * 512 + d] = h;
  Wl[(long)o * 512 + d] = f2bf_rn(v - bf2f(h));
}

// ------- bf16x3 MFMA GEMM, dual geometry (NW=2: 128x128/8 waves; NW=1: 64x64/4 waves) -------
// R0-R8 conclusion: 2-barrier structure is at its shape ceiling (~500 TF at this size);
// pick geometry per shape: 128x128 for big-N (least staging), 64x64 for small-N (grid >= 4/CU).
// Bank swizzle: row r stores k-chunks rotated by (r>>1)&3.
// EPI 2: relu(v+bias[n]) scatter to (spk,b,c,l) fp32 (final) -> C.
// EPI 3: n<512 -> fp32 xr (Cf); else SILU -> fp32 (Cf2). (fp32: same 4B as packed, no VALU.)
// EPI 4: n<512: softplus(v+bias[n]) -> fp32 (Cf); 512<=n<544 -> C2 (bc, 32).
// EPI 5: hi/lo plane store -> Ch/Cl (stride 256)  [y feeds MFMA staging -> planar].
template <int EPI, int NBN, int NW>
__global__ __launch_bounds__(256 * NW) void gemm_mfma(const u16* __restrict__ Ahp,
                                                      const u16* __restrict__ Alp, int lda,
                                                      const u16* __restrict__ Whp,
                                                      const u16* __restrict__ Wlp, int K,
                                                      float* __restrict__ C,
                                                      float* __restrict__ C2,
                                                      float* __restrict__ Cf,
                                                      float* __restrict__ Cf2,
                                                      u16* __restrict__ Ch, u16* __restrict__ Cl,
                                                      const float* __restrict__ bias) {
  constexpr int BM = 64 * NW;             // tile M = tile N
  constexpr int MI = 2 * NW;              // m-fragments per wave
  constexpr int WCN = 2 * NW;             // wave-grid columns
  constexpr int MPX = (M_ROWS / BM) / 8;  // m-tiles per xcd
  __shared__ u16 Ah[BM * 32], Al[BM * 32];
  __shared__ u16 Wh[BM * 32], Wl[BM * 32];
  int g = blockIdx.x;
  int bm = (g & 7) * MPX + (g >> 3) / NBN;
  int bn = (g >> 3) % NBN;
  long m0 = (long)bm * BM, n0 = (long)bn * BM;
  int tid = threadIdx.x;
  int w = tid >> 6, L = tid & 63;
  int q = L >> 4, r16 = L & 15;
  int wr = w / WCN, wc = w % WCN;
  int wm = wr * (16 * MI), wn = wc * 32;
  float4v acc[MI][2];
#pragma unroll
  for (int i = 0; i < MI; ++i)
#pragma unroll
    for (int j = 0; j < 2; ++j) acc[i][j] = (float4v){0.f, 0.f, 0.f, 0.f};

  int lrow = L >> 2;                          // row within 16-row chunk
  int lcol = (((L & 3) - (L >> 3)) & 3) * 8;  // swizzled fetch
  int rchunk = (q + (r16 >> 1)) & 3;          // physical chunk for logical q at row r16

  for (int k0 = 0; k0 < K; k0 += 32) {
    {
      int row = w * 16 + lrow;  // all waves together cover BM rows of A and of W
      long ga = (m0 + row) * (long)lda + k0 + lcol;
      gl_lds16(&Ahp[ga], &Ah[w * 512]);
      gl_lds16(&Alp[ga], &Al[w * 512]);
      long gw = (n0 + row) * (long)K + k0 + lcol;
      gl_lds16(&Whp[gw], &Wh[w * 512]);
      gl_lds16(&Wlp[gw], &Wl[w * 512]);
    }
    __syncthreads();
    short8 ah[MI], al[MI], bh[2], bl[2];
#pragma unroll
    for (int i = 0; i < MI; ++i) {
      int mr = wm + i * 16 + r16;
      ah[i] = *(const short8*)&Ah[mr * 32 + rchunk * 8];
      al[i] = *(const short8*)&Al[mr * 32 + rchunk * 8];
    }
#pragma unroll
    for (int j = 0; j < 2; ++j) {
      int nr = wn + j * 16 + r16;
      bh[j] = *(const short8*)&Wh[nr * 32 + rchunk * 8];
      bl[j] = *(const short8*)&Wl[nr * 32 + rchunk * 8];
    }
#pragma unroll
    for (int i = 0; i < MI; ++i)
#pragma unroll
      for (int j = 0; j < 2; ++j) {
        acc[i][j] = __builtin_amdgcn_mfma_f32_16x16x32_bf16(ah[i], bh[j], acc[i][j], 0, 0, 0);
        acc[i][j] = __builtin_amdgcn_mfma_f32_16x16x32_bf16(al[i], bh[j], acc[i][j], 0, 0, 0);
        acc[i][j] = __builtin_amdgcn_mfma_f32_16x16x32_bf16(ah[i], bl[j], acc[i][j], 0, 0, 0);
      }
    __syncthreads();
  }

  // D layout (16x16x32): row = q*4 + r, col = r16
#pragma unroll
  for (int i = 0; i < MI; ++i) {
    int m = (int)m0 + wm + i * 16 + q * 4;
#pragma unroll
    for (int j = 0; j < 2; ++j) {
      int n = (int)n0 + wn + j * 16 + r16;
      if (EPI == 3) {
        if (n < 512) {
#pragma unroll
          for (int r = 0; r < 4; ++r) Cf[(long)(m + r) * 512 + n] = acc[i][j][r];
        } else {
          int nn = n & 511;
#pragma unroll
          for (int r = 0; r < 4; ++r) {
            float zv = acc[i][j][r];
            Cf2[(long)(m + r) * 512 + nn] = zv / (1.f + __expf(-zv));  // silu baked in
          }
        }
      } else if (EPI == 4) {
        if (n < 512) {
          float vb = bias[n];
#pragma unroll
          for (int r = 0; r < 4; ++r) {
            float t = acc[i][j][r] + vb;
            t = (t > 20.f) ? t : __logf(1.f + __expf(t));
            Cf[(long)(m + r) * 512 + n] = t;
          }
        } else if (n < 544) {
#pragma unroll
          for (int r = 0; r < 4; ++r) C2[(long)(m + r) * 32 + (n - 512)] = acc[i][j][r];
        }
      } else if (EPI == 5) {
#pragma unroll
        for (int r = 0; r < 4; ++r) {
          float v = acc[i][j][r];
          u16 h = f2bf_rn(v);
          Ch[(long)(m + r) * 256 + n] = h;
          Cl[(long)(m + r) * 256 + n] = f2bf_rn(v - bf2f(h));
        }
      } else {  // EPI == 2
        float vb = bias[n];
        int spk = n >> 8, c = n & 255;
        int b = m >> 11, l = m & 2047;
        float4v v;
#pragma unroll
        for (int r = 0; r < 4; ++r) {
          float t = acc[i][j][r] + vb;
          v[r] = t > 0.f ? t : 0.f;
        }
        *(float4v*)&C[(((long)(spk * BATCH + b)) * CIN + c) * L_SEQ + l] = v;
      }
    }
  }
}

// ------ depthwise causal conv(4) + bias + SiLU; xr fp32 in, xc planar out ------
__global__ __launch_bounds__(256) void conv_silu(const float* __restrict__ xr,
                                                 const float* __restrict__ cw,
                                                 const float* __restrict__ cb,
                                                 u16* __restrict__ xch, u16* __restrict__ xcl) {
  int tid = threadIdx.x;
  int d = (tid & 127) * 4;
  int r0 = blockIdx.x * 32 + (tid >> 7) * 16;  // gridDim.x = M_ROWS/32
  float4v wv[4];
#pragma unroll
  for (int e = 0; e < 4; ++e) wv[e] = *(const float4v*)&cw[(d + e) * 4];
  float4v bias4 = *(const float4v*)&cb[d];
  float4v x0 = {0.f, 0.f, 0.f, 0.f}, x1 = x0, x2 = x0, x3;
  if ((r0 & 2047) != 0) {
#pragma unroll
    for (int p = 0; p < 3; ++p) {
      float4v xv = *(const float4v*)&xr[(long)(r0 - 3 + p) * 512 + d];
      if (p == 0) x0 = xv;
      else if (p == 1) x1 = xv;
      else x2 = xv;
    }
  }
#pragma unroll 4
  for (int t = 0; t < 16; ++t) {
    long row = (long)(r0 + t) * 512 + d;
    x3 = *(const float4v*)&xr[row];
    ushort4v oh, ol;
#pragma unroll
    for (int e = 0; e < 4; ++e) {
      float a = bias4[e] + wv[e][0] * x0[e] + wv[e][1] * x1[e] + wv[e][2] * x2[e] +
                wv[e][3] * x3[e];
      float v = a / (1.f + __expf(-a));
      u16 h = f2bf_rn(v);
      oh[e] = h;
      ol[e] = f2bf_rn(v - bf2f(h));
    }
    *(ushort4v*)&xch[row] = oh;
    *(ushort4v*)&xcl[row] = ol;
    x0 = x1;
    x1 = x2;
    x2 = x3;
  }
}

// dA powers from e1 via binary recombination (structured-A fast path)
#define DA_CHAIN(e1)                                                         \
  float e2 = (e1) * (e1), e4 = e2 * e2, e8 = e4 * e4;                        \
  float dA[16];                                                              \
  dA[0] = (e1);      dA[1] = e2;           dA[2] = e2 * (e1);                \
  dA[3] = e4;        dA[4] = e4 * (e1);    dA[5] = e4 * e2;                  \
  dA[6] = dA[5] * (e1); dA[7] = e8;        dA[8] = e8 * (e1);                \
  dA[9] = e8 * e2;   dA[10] = dA[9] * (e1); dA[11] = e8 * e4;                \
  dA[12] = dA[11] * (e1); dA[13] = e8 * e4 * e2; dA[14] = dA[13] * (e1);     \
  dA[15] = e8 * e8;

// structured-A check: Aval[s] == (s+1)*Aval[0] within 4e-6 rel (A_log = log(1..16) pattern)
__device__ inline bool a_structured(const float* Aval) {
  bool ok = true;
#pragma unroll
  for (int s = 1; s < 16; ++s) {
    float ideal = Aval[0] * (s + 1);
    ok = ok && (fabsf(Aval[s] - ideal) <= 4e-6f * fabsf(ideal));
  }
  return ok;
}

// ---------------- chunked selective scan: thread per (b,d), 16 states in registers ------------
__global__ __launch_bounds__(256) void scan_pass1(const float* __restrict__ dx,
                                                  const u16* __restrict__ xch,
                                                  const u16* __restrict__ xcl,
                                                  const float* __restrict__ bc,
                                                  const float* __restrict__ A_log,
                                                  float* __restrict__ P,
                                                  float* __restrict__ Hl) {
  int b = blockIdx.z, c = blockIdx.y;
  int tid = threadIdx.x;
  int d = blockIdx.x * 256 + tid;
  __shared__ float sBC[LC][32];
  const long base = (long)b * L_SEQ + (long)c * LC;
  ((float4v*)sBC)[tid] = ((const float4v*)&bc[base * 32])[tid];
  float Aval[16];
  {
    float4v a[4];
#pragma unroll
    for (int g = 0; g < 4; ++g) a[g] = *(const float4v*)&A_log[d * 16 + g * 4];
#pragma unroll
    for (int s = 0; s < 16; ++s) Aval[s] = -__expf(a[s >> 2][s & 3]);
  }
  bool chain = a_structured(Aval);
  __syncthreads();
  float h[16];
#pragma unroll
  for (int s = 0; s < 16; ++s) h[s] = 0.f;
  float sd = 0.f;
  if (chain) {
    float a1 = Aval[0];
#pragma unroll 4
    for (int t = 0; t < LC; ++t) {
      long off = (base + t) * 512 + d;
      float dlv = dx[off];
      float xv = bf2f(xch[off]) + bf2f(xcl[off]);
      float w = dlv * xv;
      sd += dlv;
      float4v Bv[4];
#pragma unroll
      for (int g = 0; g < 4; ++g) Bv[g] = *(const float4v*)&sBC[t][g * 4];
      float e1 = __expf(dlv * a1);
      DA_CHAIN(e1)
#pragma unroll
      for (int s = 0; s < 16; ++s) h[s] = dA[s] * h[s] + w * Bv[s >> 2][s & 3];
    }
  } else {
#pragma unroll 4
    for (int t = 0; t < LC; ++t) {
      long off = (base + t) * 512 + d;
      float dlv = dx[off];
      float xv = bf2f(xch[off]) + bf2f(xcl[off]);
      float w = dlv * xv;
      sd += dlv;
      float4v Bv[4];
#pragma unroll
      for (int g = 0; g < 4; ++g) Bv[g] = *(const float4v*)&sBC[t][g * 4];
#pragma unroll
      for (int s = 0; s < 16; ++s) {
        float dA = __expf(dlv * Aval[s]);
        h[s] = dA * h[s] + w * Bv[s >> 2][s & 3];
      }
    }
  }
  long idx = (((long)b * NC + c) * 512 + d) * 16;
#pragma unroll
  for (int g = 0; g < 4; ++g) {
    float4v pv, hv;
#pragma unroll
    for (int e = 0; e < 4; ++e) {
      pv[e] = __expf(Aval[g * 4 + e] * sd);
      hv[e] = h[g * 4 + e];
    }
    *(float4v*)&P[idx + g * 4] = pv;
    *(float4v*)&Hl[idx + g * 4] = hv;
  }
}

__global__ __launch_bounds__(256) void scan_combine(const float* __restrict__ P,
                                                    const float* __restrict__ Hl,
                                                    float* __restrict__ H0) {
  int idx = blockIdx.x * 256 + threadIdx.x;  // over B*512*16 = 65536
  int b = idx >> 13;
  int ds = idx & 8191;
  float h = 0.f;
#pragma unroll 8
  for (int c = 0; c < NC; ++c) {
    long off = (((long)b * NC + c) << 13) + ds;
    H0[off] = h;
    h = P[off] * h + Hl[off];
  }
}

__global__ __launch_bounds__(256) void scan_pass2(const float* __restrict__ dx,
                                                  u16* __restrict__ yh, u16* __restrict__ yl,
                                                  const u16* __restrict__ xch,
                                                  const u16* __restrict__ xcl,
                                                  const float* __restrict__ bc,
                                                  const float* __restrict__ zs,
                                                  const float* __restrict__ A_log,
                                                  const float* __restrict__ Dp,
                                                  const float* __restrict__ H0) {
  int b = blockIdx.z, c = blockIdx.y;
  int tid = threadIdx.x;
  int d = blockIdx.x * 256 + tid;
  __shared__ float sBC[LC][32];
  const long base = (long)b * L_SEQ + (long)c * LC;
  ((float4v*)sBC)[tid] = ((const float4v*)&bc[base * 32])[tid];
  float Aval[16];
  {
    float4v a[4];
#pragma unroll
    for (int g = 0; g < 4; ++g) a[g] = *(const float4v*)&A_log[d * 16 + g * 4];
#pragma unroll
    for (int s = 0; s < 16; ++s) Aval[s] = -__expf(a[s >> 2][s & 3]);
  }
  bool chain = a_structured(Aval);
  float Dval = Dp[d];
  float h[16];
  {
    long hidx = (((long)b * NC + c) * 512 + d) * 16;
#pragma unroll
    for (int g = 0; g < 4; ++g) {
      float4v hv = *(const float4v*)&H0[hidx + g * 4];
#pragma unroll
      for (int e = 0; e < 4; ++e) h[g * 4 + e] = hv[e];
    }
  }
  __syncthreads();
  if (chain) {
    float a1 = Aval[0];
#pragma unroll 2
    for (int t = 0; t < LC; ++t) {
      long off = (base + t) * 512 + d;
      float dlv = dx[off];
      float xv = bf2f(xch[off]) + bf2f(xcl[off]);
      float z1 = zs[off];  // silu already applied in EPI3
      float w = dlv * xv;
      float4v Bv[4], Cv[4];
#pragma unroll
      for (int g = 0; g < 4; ++g) {
        Bv[g] = *(const float4v*)&sBC[t][g * 4];
        Cv[g] = *(const float4v*)&sBC[t][16 + g * 4];
      }
      float e1 = __expf(dlv * a1);
      DA_CHAIN(e1)
      float ya = 0.f, yb = 0.f, yc2 = 0.f, yd = 0.f;
#pragma unroll
      for (int s = 0; s < 4; ++s) {
        h[s] = dA[s] * h[s] + w * Bv[0][s];
        ya += h[s] * Cv[0][s];
      }
#pragma unroll
      for (int s = 4; s < 8; ++s) {
        h[s] = dA[s] * h[s] + w * Bv[1][s - 4];
        yb += h[s] * Cv[1][s - 4];
      }
#pragma unroll
      for (int s = 8; s < 12; ++s) {
        h[s] = dA[s] * h[s] + w * Bv[2][s - 8];
        yc2 += h[s] * Cv[2][s - 8];
      }
#pragma unroll
      for (int s = 12; s < 16; ++s) {
        h[s] = dA[s] * h[s] + w * Bv[3][s - 12];
        yd += h[s] * Cv[3][s - 12];
      }
      float yv = (ya + yb) + (yc2 + yd);
      float yf = (yv + xv * Dval) * z1;
      u16 hh = f2bf_rn(yf);
      yh[off] = hh;
      yl[off] = f2bf_rn(yf - bf2f(hh));
    }
  } else {
#pragma unroll 2
    for (int t = 0; t < LC; ++t) {
      long off = (base + t) * 512 + d;
      float dlv = dx[off];
      float xv = bf2f(xch[off]) + bf2f(xcl[off]);
      float z1 = zs[off];
      float w = dlv * xv;
      float4v Bv[4], Cv[4];
#pragma unroll
      for (int g = 0; g < 4; ++g) {
        Bv[g] = *(const float4v*)&sBC[t][g * 4];
        Cv[g] = *(const float4v*)&sBC[t][16 + g * 4];
      }
      float ya = 0.f, yb = 0.f, yc2 = 0.f, yd = 0.f;
#pragma unroll
      for (int s = 0; s < 4; ++s) {
        float dA = __expf(dlv * Aval[s]);
        h[s] = dA * h[s] + w * Bv[0][s];
        ya += h[s] * Cv[0][s];
      }
#pragma unroll
      for (int s = 4; s < 8; ++s) {
        float dA = __expf(dlv * Aval[s]);
        h[s] = dA * h[s] + w * Bv[1][s - 4];
        yb += h[s] * Cv[1][s - 4];
      }
#pragma unroll
      for (int s = 8; s < 12; ++s) {
        float dA = __expf(dlv * Aval[s]);
        h[s] = dA * h[s] + w * Bv[2][s - 8];
        yc2 += h[s] * Cv[2][s - 8];
      }
#pragma unroll
      for (int s = 12; s < 16; ++s) {
        float dA = __expf(dlv * Aval[s]);
        h[s] = dA * h[s] + w * Bv[3][s - 12];
        yd += h[s] * Cv[3][s - 12];
      }
      float yv = (ya + yb) + (yc2 + yd);
      float yf = (yv + xv * Dval) * z1;
      u16 hh = f2bf_rn(yf);
      yh[off] = hh;
      yl[off] = f2bf_rn(yf - bf2f(hh));
    }
  }
}

extern "C" void kernel_launch(void* const* d_in, const int* in_sizes, int n_in, void* d_out,
                              int out_size, void* d_ws, size_t ws_size, hipStream_t stream) {
  const float* input = (const float*)d_in[0];
  const float* in_proj_w = (const float*)d_in[1];
  const float* conv_w = (const float*)d_in[2];
  const float* conv_b = (const float*)d_in[3];
  const float* x_proj_w = (const float*)d_in[4];
  const float* dt_proj_w = (const float*)d_in[5];
  const float* dt_proj_b = (const float*)d_in[6];
  const float* A_log = (const float*)d_in[7];
  const float* Dp = (const float*)d_in[8];
  const float* out_proj_w = (const float*)d_in[9];
  const float* out_lin_w = (const float*)d_in[10];
  const float* out_lin_b = (const float*)d_in[11];

  char* ws = (char*)d_ws;
  u16* buf_xh = (u16*)(ws);                  // 8.39 MB
  u16* buf_xl = (u16*)(ws + 8388608);        // 8.39 MB
  float* buf_xr = (float*)(ws + 16777216);   // 33.55 MB fp32 xr (P/Hl alias after conv; then y)
  float* buf_zs = (float*)(ws + 50331648);   // 33.55 MB fp32 silu(z)
  u16* buf_xch = (u16*)(ws + 83886080);      // 16 MB
  u16* buf_xcl = (u16*)(ws + 100663296);     // 16 MB
  float* buf_bc = (float*)(ws + 117440512);  // 2 MB (M_ROWS x 32)
  u16* buf_wch = (u16*)(ws + 119537664);     // 0.5 MB
  u16* buf_wcl = (u16*)(ws + 120061952);     // 0.5 MB
  float* buf_d = (float*)(ws + 120586240);   // 33.55 MB fp32 delta
  u16* buf_wd0h = (u16*)(ws + 154140672);    // 640x512 planes (576 live + 64 zero-pad rows)
  u16* buf_wd0l = (u16*)(ws + 154796032);
  u16* buf_wd1h = (u16*)(ws + 155451392);
  u16* buf_wd1l = (u16*)(ws + 156106752);
  u16* buf_wth = (u16*)(ws + 156762112);     // 0.5 MB reusable weight scratch
  u16* buf_wtl = (u16*)(ws + 157286400);
  float* buf_P = (float*)(ws + 16777216);    // 16.78 MB (xr dead after conv) — R0-proven layout
  float* buf_Hl = (float*)(ws + 33554432);   // 16.78 MB
  float* buf_H0 = (float*)ws;                // 16.78 MB (x planes dead during scan)
  u16* buf_yh = (u16*)(ws + 16777216);       // over P (dead after combine)
  u16* buf_yl = (u16*)(ws + 33554432);       // over Hl

  build_wd<<<dim3(2, 640), 256, 0, stream>>>(x_proj_w, dt_proj_w, buf_wd0h, buf_wd0l);
  build_wd<<<dim3(2, 640), 256, 0, stream>>>(x_proj_w + 48 * 512, dt_proj_w + 512 * 16, buf_wd1h,
                                             buf_wd1l);
  build_wcomb<<<dim3(2, 512), 256, 0, stream>>>(out_lin_w, out_proj_w + (long)256 * 512, buf_wch,
                                                buf_wcl);
  transpose_in<<<dim3(64, 8, 8), dim3(32, 8), 0, stream>>>(input, buf_xh, buf_xl);

  for (int i = 0; i < 2; ++i) {
    split_pack<<<1024, 256, 0, stream>>>(in_proj_w + (long)i * 1024 * 256, buf_wth, buf_wtl,
                                         1024 * 256);
    gemm_mfma<3, 8, 2><<<1024, 512, 0, stream>>>(buf_xh, buf_xl, 256, buf_wth, buf_wtl, 256,
                                                 nullptr, nullptr, buf_xr, buf_zs, nullptr,
                                                 nullptr, nullptr);
    conv_silu<<<512, 256, 0, stream>>>(buf_xr, conv_w + i * 512 * 4, conv_b + i * 512,
                                       buf_xch, buf_xcl);
    gemm_mfma<4, 5, 2><<<640, 512, 0, stream>>>(
        buf_xch, buf_xcl, 512, (i == 0) ? buf_wd0h : buf_wd1h, (i == 0) ? buf_wd0l : buf_wd1l,
        512, nullptr, buf_bc, buf_d, nullptr, nullptr, nullptr, dt_proj_b + i * 512);
    scan_pass1<<<dim3(2, NC, 8), 256, 0, stream>>>(buf_d, buf_xch, buf_xcl, buf_bc,
                                                   A_log + (long)i * 512 * 16, buf_P, buf_Hl);
    scan_combine<<<256, 256, 0, stream>>>(buf_P, buf_Hl, buf_H0);
    scan_pass2<<<dim3(2, NC, 8), 256, 0, stream>>>(buf_d, buf_yh, buf_yl, buf_xch, buf_xcl,
                                                   buf_bc, buf_zs,
                                                   A_log + (long)i * 512 * 16, Dp + i * 512,
                                                   buf_H0);
    if (i == 0) {
      split_pack<<<512, 256, 0, stream>>>(out_proj_w, buf_wth, buf_wtl, 256 * 512);
      gemm_mfma<5, 4, 1><<<1024, 256, 0, stream>>>(buf_yh, buf_yl, 512, buf_wth, buf_wtl, 512,
                                                   nullptr, nullptr, nullptr, nullptr, buf_xh,
                                                   buf_xl, nullptr);
    } else {
      gemm_mfma<2, 8, 1><<<2048, 256, 0, stream>>>(buf_yh, buf_yl, 512, buf_wch, buf_wcl, 512,
                                                   (float*)d_out, nullptr, nullptr, nullptr,
                                                   nullptr, nullptr, out_lin_b);
    }
  }
}

// Round 13
// 485.333 us; speedup vs baseline: 1.0325x; 1.0325x over previous
//
#include <hip/hip_runtime.h>
#include <cmath>

#define L_SEQ 2048
#define BATCH 8
#define CIN 256
#define DIN 512
#define M_ROWS (BATCH * L_SEQ)  // 16384
#define NC 32                   // scan chunks
#define LC 64                   // chunk length

typedef __attribute__((ext_vector_type(8))) short short8;
typedef __attribute__((ext_vector_type(4))) unsigned short ushort4v;
typedef __attribute__((ext_vector_type(4))) float float4v;
typedef unsigned short u16;
typedef unsigned int u32;

__device__ inline u16 f2bf_rn(float x) {
  union { float f; unsigned u; } v;
  v.f = x;
  unsigned r = v.u + 0x7FFF + ((v.u >> 16) & 1);
  return (u16)(r >> 16);
}
__device__ inline float bf2f(u16 h) {
  union { unsigned u; float f; } v;
  v.u = ((unsigned)h) << 16;
  return v.f;
}

// async 16B global->LDS (gfx950). LDS dest = wave-uniform base + lane*16.
__device__ inline void gl_lds16(const u16* g, u16* l) {
  __builtin_amdgcn_global_load_lds(
      (const __attribute__((address_space(1))) unsigned int*)(const void*)g,
      (__attribute__((address_space(3))) unsigned int*)(void*)l, 16, 0, 0);
}

// ---------------- transpose (B,C,L) -> (B,L,C), hi/lo bf16 planes ----------------
__global__ __launch_bounds__(256) void transpose_in(const float* __restrict__ in,
                                                    u16* __restrict__ xh, u16* __restrict__ xl) {
  __shared__ float tile[32][33];
  int b = blockIdx.z;
  int l0 = blockIdx.x * 32, c0 = blockIdx.y * 32;
  int tx = threadIdx.x, ty = threadIdx.y;  // 32 x 8
#pragma unroll
  for (int k = 0; k < 4; ++k)
    tile[ty + k * 8][tx] = in[(long)(b * CIN + c0 + ty + k * 8) * L_SEQ + l0 + tx];
  __syncthreads();
#pragma unroll
  for (int k = 0; k < 4; ++k) {
    float v = tile[tx][ty + k * 8];
    long o = (long)(b * L_SEQ + l0 + ty + k * 8) * CIN + c0 + tx;
    u16 h = f2bf_rn(v);
    xh[o] = h;
    xl[o] = f2bf_rn(v - bf2f(h));
  }
}

// ---------------- weight packing to planes ----------------
__global__ __launch_bounds__(256) void split_pack(const float* __restrict__ in,
                                                  u16* __restrict__ oh, u16* __restrict__ ol,
                                                  int n) {
  int i = blockIdx.x * 256 + threadIdx.x;
  if (i < n) {
    float v = in[i];
    u16 h = f2bf_rn(v);
    oh[i] = h;
    ol[i] = f2bf_rn(v - bf2f(h));
  }
}

// Wd (640 x 512): rows 0..511 = dt_proj_w @ x_proj_w[0:16]; 512..543 = B,C rows; 544..639 = 0
__global__ __launch_bounds__(256) void build_wd(const float* __restrict__ xpw,
                                                const float* __restrict__ dtw,
                                                u16* __restrict__ Wh, u16* __restrict__ Wl) {
  int k = blockIdx.x * 256 + threadIdx.x;  // 0..511
  int n = blockIdx.y;                      // 0..639
  float v;
  if (n < 512) {
    v = 0.f;
#pragma unroll
    for (int r = 0; r < 16; ++r) v += dtw[n * 16 + r] * xpw[r * 512 + k];
  } else if (n < 544) {
    v = xpw[(16 + n - 512) * 512 + k];
  } else {
    v = 0.f;
  }
  u16 h = f2bf_rn(v);
  Wh[(long)n * 512 + k] = h;
  Wl[(long)n * 512 + k] = f2bf_rn(v - bf2f(h));
}

// W_comb (512 x 512): out_lin_w (512x256) @ out_proj_w[layer1] (256x512)
__global__ __launch_bounds__(256) void build_wcomb(const float* __restrict__ olw,
                                                   const float* __restrict__ opw,
                                                   u16* __restrict__ Wh, u16* __restrict__ Wl) {
  int d = blockIdx.x * 256 + threadIdx.x;  // 0..511
  int o = blockIdx.y;                      // 0..511
  float v = 0.f;
#pragma unroll 4
  for (int c = 0; c < 256; ++c) v += olw[o * 256 + c] * opw[(long)c * 512 + d];
  u16 h = f2bf_rn(v);
  Wh[(long)o * 512 + d] = h;
  Wl[(long)o * 512 + d] = f2bf_rn(v - bf2f(h));
}

// ------- bf16x3 MFMA GEMM, dual geometry (NW=2: 128x128/8 waves; NW=1: 64x64/4 waves) -------
// R0-R8 conclusion: 2-barrier structure is at its shape ceiling (~500 TF at this size);
// pick geometry per shape: 128x128 for big-N (least staging), 64x64 for small-N (grid >= 4/CU).
// Bank swizzle: row r stores k-chunks rotated by (r>>1)&3.
// EPI 2: relu(v+bias[n]) scatter to (spk,b,c,l) fp32 (final) -> C.
// EPI 3: n<512 -> fp32 xr (Cf); else SILU -> fp32 (Cf2). (fp32: same 4B as packed, no VALU.)
// EPI 4: n<512: softplus(v+bias[n]) -> fp32 (Cf); 512<=n<544 -> C2 (bc, 32).
// EPI 5: hi/lo plane store -> Ch/Cl (stride 256)  [y feeds MFMA staging -> planar].
template <int EPI, int NBN, int NW>
__global__ __launch_bounds__(256 * NW) void gemm_mfma(const u16* __restrict__ Ahp,
                                                      const u16* __restrict__ Alp, int lda,
                                                      const u16* __restrict__ Whp,
                                                      const u16* __restrict__ Wlp, int K,
                                                      float* __restrict__ C,
                                                      float* __restrict__ C2,
                                                      float* __restrict__ Cf,
                                                      float* __restrict__ Cf2,
                                                      u16* __restrict__ Ch, u16* __restrict__ Cl,
                                                      const float* __restrict__ bias) {
  constexpr int BM = 64 * NW;             // tile M = tile N
  constexpr int MI = 2 * NW;              // m-fragments per wave
  constexpr int WCN = 2 * NW;             // wave-grid columns
  constexpr int MPX = (M_ROWS / BM) / 8;  // m-tiles per xcd
  __shared__ u16 Ah[BM * 32], Al[BM * 32];
  __shared__ u16 Wh[BM * 32], Wl[BM * 32];
  int g = blockIdx.x;
  int bm = (g & 7) * MPX + (g >> 3) / NBN;
  int bn = (g >> 3) % NBN;
  long m0 = (long)bm * BM, n0 = (long)bn * BM;
  int tid = threadIdx.x;
  int w = tid >> 6, L = tid & 63;
  int q = L >> 4, r16 = L & 15;
  int wr = w / WCN, wc = w % WCN;
  int wm = wr * (16 * MI), wn = wc * 32;
  float4v acc[MI][2];
#pragma unroll
  for (int i = 0; i < MI; ++i)
#pragma unroll
    for (int j = 0; j < 2; ++j) acc[i][j] = (float4v){0.f, 0.f, 0.f, 0.f};

  int lrow = L >> 2;                          // row within 16-row chunk
  int lcol = (((L & 3) - (L >> 3)) & 3) * 8;  // swizzled fetch
  int rchunk = (q + (r16 >> 1)) & 3;          // physical chunk for logical q at row r16

  for (int k0 = 0; k0 < K; k0 += 32) {
    {
      int row = w * 16 + lrow;  // all waves together cover BM rows of A and of W
      long ga = (m0 + row) * (long)lda + k0 + lcol;
      gl_lds16(&Ahp[ga], &Ah[w * 512]);
      gl_lds16(&Alp[ga], &Al[w * 512]);
      long gw = (n0 + row) * (long)K + k0 + lcol;
      gl_lds16(&Whp[gw], &Wh[w * 512]);
      gl_lds16(&Wlp[gw], &Wl[w * 512]);
    }
    __syncthreads();
    short8 ah[MI], al[MI], bh[2], bl[2];
#pragma unroll
    for (int i = 0; i < MI; ++i) {
      int mr = wm + i * 16 + r16;
      ah[i] = *(const short8*)&Ah[mr * 32 + rchunk * 8];
      al[i] = *(const short8*)&Al[mr * 32 + rchunk * 8];
    }
#pragma unroll
    for (int j = 0; j < 2; ++j) {
      int nr = wn + j * 16 + r16;
      bh[j] = *(const short8*)&Wh[nr * 32 + rchunk * 8];
      bl[j] = *(const short8*)&Wl[nr * 32 + rchunk * 8];
    }
#pragma unroll
    for (int i = 0; i < MI; ++i)
#pragma unroll
      for (int j = 0; j < 2; ++j) {
        acc[i][j] = __builtin_amdgcn_mfma_f32_16x16x32_bf16(ah[i], bh[j], acc[i][j], 0, 0, 0);
        acc[i][j] = __builtin_amdgcn_mfma_f32_16x16x32_bf16(al[i], bh[j], acc[i][j], 0, 0, 0);
        acc[i][j] = __builtin_amdgcn_mfma_f32_16x16x32_bf16(ah[i], bl[j], acc[i][j], 0, 0, 0);
      }
    __syncthreads();
  }

  // D layout (16x16x32): row = q*4 + r, col = r16
#pragma unroll
  for (int i = 0; i < MI; ++i) {
    int m = (int)m0 + wm + i * 16 + q * 4;
#pragma unroll
    for (int j = 0; j < 2; ++j) {
      int n = (int)n0 + wn + j * 16 + r16;
      if (EPI == 3) {
        if (n < 512) {
#pragma unroll
          for (int r = 0; r < 4; ++r) Cf[(long)(m + r) * 512 + n] = acc[i][j][r];
        } else {
          int nn = n & 511;
#pragma unroll
          for (int r = 0; r < 4; ++r) {
            float zv = acc[i][j][r];
            Cf2[(long)(m + r) * 512 + nn] = zv / (1.f + __expf(-zv));  // silu baked in
          }
        }
      } else if (EPI == 4) {
        if (n < 512) {
          float vb = bias[n];
#pragma unroll
          for (int r = 0; r < 4; ++r) {
            float t = acc[i][j][r] + vb;
            t = (t > 20.f) ? t : __logf(1.f + __expf(t));
            Cf[(long)(m + r) * 512 + n] = t;
          }
        } else if (n < 544) {
#pragma unroll
          for (int r = 0; r < 4; ++r) C2[(long)(m + r) * 32 + (n - 512)] = acc[i][j][r];
        }
      } else if (EPI == 5) {
#pragma unroll
        for (int r = 0; r < 4; ++r) {
          float v = acc[i][j][r];
          u16 h = f2bf_rn(v);
          Ch[(long)(m + r) * 256 + n] = h;
          Cl[(long)(m + r) * 256 + n] = f2bf_rn(v - bf2f(h));
        }
      } else {  // EPI == 2
        float vb = bias[n];
        int spk = n >> 8, c = n & 255;
        int b = m >> 11, l = m & 2047;
        float4v v;
#pragma unroll
        for (int r = 0; r < 4; ++r) {
          float t = acc[i][j][r] + vb;
          v[r] = t > 0.f ? t : 0.f;
        }
        *(float4v*)&C[(((long)(spk * BATCH + b)) * CIN + c) * L_SEQ + l] = v;
      }
    }
  }
}

// ------ depthwise causal conv(4) + bias + SiLU; xr fp32 in, xc planar out ------
__global__ __launch_bounds__(256) void conv_silu(const float* __restrict__ xr,
                                                 const float* __restrict__ cw,
                                                 const float* __restrict__ cb,
                                                 u16* __restrict__ xch, u16* __restrict__ xcl) {
  int tid = threadIdx.x;
  int d = (tid & 127) * 4;
  int r0 = blockIdx.x * 32 + (tid >> 7) * 16;  // gridDim.x = M_ROWS/32
  float4v wv[4];
#pragma unroll
  for (int e = 0; e < 4; ++e) wv[e] = *(const float4v*)&cw[(d + e) * 4];
  float4v bias4 = *(const float4v*)&cb[d];
  float4v x0 = {0.f, 0.f, 0.f, 0.f}, x1 = x0, x2 = x0, x3;
  if ((r0 & 2047) != 0) {
#pragma unroll
    for (int p = 0; p < 3; ++p) {
      float4v xv = *(const float4v*)&xr[(long)(r0 - 3 + p) * 512 + d];
      if (p == 0) x0 = xv;
      else if (p == 1) x1 = xv;
      else x2 = xv;
    }
  }
#pragma unroll 4
  for (int t = 0; t < 16; ++t) {
    long row = (long)(r0 + t) * 512 + d;
    x3 = *(const float4v*)&xr[row];
    ushort4v oh, ol;
#pragma unroll
    for (int e = 0; e < 4; ++e) {
      float a = bias4[e] + wv[e][0] * x0[e] + wv[e][1] * x1[e] + wv[e][2] * x2[e] +
                wv[e][3] * x3[e];
      float v = a / (1.f + __expf(-a));
      u16 h = f2bf_rn(v);
      oh[e] = h;
      ol[e] = f2bf_rn(v - bf2f(h));
    }
    *(ushort4v*)&xch[row] = oh;
    *(ushort4v*)&xcl[row] = ol;
    x0 = x1;
    x1 = x2;
    x2 = x3;
  }
}

// dA powers from e1 via binary recombination (structured-A fast path)
#define DA_CHAIN(e1)                                                         \
  float e2 = (e1) * (e1), e4 = e2 * e2, e8 = e4 * e4;                        \
  float dA[16];                                                              \
  dA[0] = (e1);      dA[1] = e2;           dA[2] = e2 * (e1);                \
  dA[3] = e4;        dA[4] = e4 * (e1);    dA[5] = e4 * e2;                  \
  dA[6] = dA[5] * (e1); dA[7] = e8;        dA[8] = e8 * (e1);                \
  dA[9] = e8 * e2;   dA[10] = dA[9] * (e1); dA[11] = e8 * e4;                \
  dA[12] = dA[11] * (e1); dA[13] = e8 * e4 * e2; dA[14] = dA[13] * (e1);     \
  dA[15] = e8 * e8;

// structured-A check: Aval[s] == (s+1)*Aval[0] within 4e-6 rel (A_log = log(1..16) pattern)
__device__ inline bool a_structured(const float* Aval) {
  bool ok = true;
#pragma unroll
  for (int s = 1; s < 16; ++s) {
    float ideal = Aval[0] * (s + 1);
    ok = ok && (fabsf(Aval[s] - ideal) <= 4e-6f * fabsf(ideal));
  }
  return ok;
}

// ---------------- chunked selective scan: thread per (b,d), 16 states in registers ------------
// pass1 outputs per-chunk state Hl and the scalar delta-sum sd; combine recomputes
// P = exp(Aval*sd) from the SAME formula/inputs pass1 would have used (bit-identical),
// saving the 16-wide P materialization (8.39 MB/layer -> 0.5 MB).
__global__ __launch_bounds__(256) void scan_pass1(const float* __restrict__ dx,
                                                  const u16* __restrict__ xch,
                                                  const u16* __restrict__ xcl,
                                                  const float* __restrict__ bc,
                                                  const float* __restrict__ A_log,
                                                  float* __restrict__ sdout,
                                                  float* __restrict__ Hl) {
  int b = blockIdx.z, c = blockIdx.y;
  int tid = threadIdx.x;
  int d = blockIdx.x * 256 + tid;
  __shared__ float sBC[LC][32];
  const long base = (long)b * L_SEQ + (long)c * LC;
  ((float4v*)sBC)[tid] = ((const float4v*)&bc[base * 32])[tid];
  ((float4v*)sBC)[tid + 256] = ((const float4v*)&bc[base * 32])[tid + 256];
  float Aval[16];
  {
    float4v a[4];
#pragma unroll
    for (int g = 0; g < 4; ++g) a[g] = *(const float4v*)&A_log[d * 16 + g * 4];
#pragma unroll
    for (int s = 0; s < 16; ++s) Aval[s] = -__expf(a[s >> 2][s & 3]);
  }
  bool chain = a_structured(Aval);
  __syncthreads();
  float h[16];
#pragma unroll
  for (int s = 0; s < 16; ++s) h[s] = 0.f;
  float sd = 0.f;
  if (chain) {
    float a1 = Aval[0];
#pragma unroll 4
    for (int t = 0; t < LC; ++t) {
      long off = (base + t) * 512 + d;
      float dlv = dx[off];
      float xv = bf2f(xch[off]) + bf2f(xcl[off]);
      float w = dlv * xv;
      sd += dlv;
      float4v Bv[4];
#pragma unroll
      for (int g = 0; g < 4; ++g) Bv[g] = *(const float4v*)&sBC[t][g * 4];
      float e1 = __expf(dlv * a1);
      DA_CHAIN(e1)
#pragma unroll
      for (int s = 0; s < 16; ++s) h[s] = dA[s] * h[s] + w * Bv[s >> 2][s & 3];
    }
  } else {
#pragma unroll 4
    for (int t = 0; t < LC; ++t) {
      long off = (base + t) * 512 + d;
      float dlv = dx[off];
      float xv = bf2f(xch[off]) + bf2f(xcl[off]);
      float w = dlv * xv;
      sd += dlv;
      float4v Bv[4];
#pragma unroll
      for (int g = 0; g < 4; ++g) Bv[g] = *(const float4v*)&sBC[t][g * 4];
#pragma unroll
      for (int s = 0; s < 16; ++s) {
        float dA = __expf(dlv * Aval[s]);
        h[s] = dA * h[s] + w * Bv[s >> 2][s & 3];
      }
    }
  }
  long idx = (((long)b * NC + c) * 512 + d) * 16;
#pragma unroll
  for (int g = 0; g < 4; ++g) {
    float4v hv;
#pragma unroll
    for (int e = 0; e < 4; ++e) hv[e] = h[g * 4 + e];
    *(float4v*)&Hl[idx + g * 4] = hv;
  }
  sdout[(((long)b * NC + c) << 9) + d] = sd;
}

__global__ __launch_bounds__(256) void scan_combine(const float* __restrict__ A_log,
                                                    const float* __restrict__ sd,
                                                    const float* __restrict__ Hl,
                                                    float* __restrict__ H0) {
  int idx = blockIdx.x * 256 + threadIdx.x;  // over B*512*16 = 65536
  int b = idx >> 13;
  int ds = idx & 8191;
  int d = ds >> 4;
  float Aval = -__expf(A_log[ds]);
  float h = 0.f;
#pragma unroll 8
  for (int c = 0; c < NC; ++c) {
    long off = (((long)b * NC + c) << 13) + ds;
    H0[off] = h;
    float P = __expf(Aval * sd[(((long)b * NC + c) << 9) + d]);
    h = P * h + Hl[off];
  }
}

__global__ __launch_bounds__(256) void scan_pass2(const float* __restrict__ dx,
                                                  u16* __restrict__ yh, u16* __restrict__ yl,
                                                  const u16* __restrict__ xch,
                                                  const u16* __restrict__ xcl,
                                                  const float* __restrict__ bc,
                                                  const float* __restrict__ zs,
                                                  const float* __restrict__ A_log,
                                                  const float* __restrict__ Dp,
                                                  const float* __restrict__ H0) {
  int b = blockIdx.z, c = blockIdx.y;
  int tid = threadIdx.x;
  int d = blockIdx.x * 256 + tid;
  __shared__ float sBC[LC][32];
  const long base = (long)b * L_SEQ + (long)c * LC;
  ((float4v*)sBC)[tid] = ((const float4v*)&bc[base * 32])[tid];
  ((float4v*)sBC)[tid + 256] = ((const float4v*)&bc[base * 32])[tid + 256];
  float Aval[16];
  {
    float4v a[4];
#pragma unroll
    for (int g = 0; g < 4; ++g) a[g] = *(const float4v*)&A_log[d * 16 + g * 4];
#pragma unroll
    for (int s = 0; s < 16; ++s) Aval[s] = -__expf(a[s >> 2][s & 3]);
  }
  bool chain = a_structured(Aval);
  float Dval = Dp[d];
  float h[16];
  {
    long hidx = (((long)b * NC + c) * 512 + d) * 16;
#pragma unroll
    for (int g = 0; g < 4; ++g) {
      float4v hv = *(const float4v*)&H0[hidx + g * 4];
#pragma unroll
      for (int e = 0; e < 4; ++e) h[g * 4 + e] = hv[e];
    }
  }
  __syncthreads();
  if (chain) {
    float a1 = Aval[0];
#pragma unroll 2
    for (int t = 0; t < LC; ++t) {
      long off = (base + t) * 512 + d;
      float dlv = dx[off];
      float xv = bf2f(xch[off]) + bf2f(xcl[off]);
      float z1 = zs[off];  // silu already applied in EPI3
      float w = dlv * xv;
      float4v Bv[4], Cv[4];
#pragma unroll
      for (int g = 0; g < 4; ++g) {
        Bv[g] = *(const float4v*)&sBC[t][g * 4];
        Cv[g] = *(const float4v*)&sBC[t][16 + g * 4];
      }
      float e1 = __expf(dlv * a1);
      DA_CHAIN(e1)
      float ya = 0.f, yb = 0.f, yc2 = 0.f, yd = 0.f;
#pragma unroll
      for (int s = 0; s < 4; ++s) {
        h[s] = dA[s] * h[s] + w * Bv[0][s];
        ya += h[s] * Cv[0][s];
      }
#pragma unroll
      for (int s = 4; s < 8; ++s) {
        h[s] = dA[s] * h[s] + w * Bv[1][s - 4];
        yb += h[s] * Cv[1][s - 4];
      }
#pragma unroll
      for (int s = 8; s < 12; ++s) {
        h[s] = dA[s] * h[s] + w * Bv[2][s - 8];
        yc2 += h[s] * Cv[2][s - 8];
      }
#pragma unroll
      for (int s = 12; s < 16; ++s) {
        h[s] = dA[s] * h[s] + w * Bv[3][s - 12];
        yd += h[s] * Cv[3][s - 12];
      }
      float yv = (ya + yb) + (yc2 + yd);
      float yf = (yv + xv * Dval) * z1;
      u16 hh = f2bf_rn(yf);
      yh[off] = hh;
      yl[off] = f2bf_rn(yf - bf2f(hh));
    }
  } else {
#pragma unroll 2
    for (int t = 0; t < LC; ++t) {
      long off = (base + t) * 512 + d;
      float dlv = dx[off];
      float xv = bf2f(xch[off]) + bf2f(xcl[off]);
      float z1 = zs[off];
      float w = dlv * xv;
      float4v Bv[4], Cv[4];
#pragma unroll
      for (int g = 0; g < 4; ++g) {
        Bv[g] = *(const float4v*)&sBC[t][g * 4];
        Cv[g] = *(const float4v*)&sBC[t][16 + g * 4];
      }
      float ya = 0.f, yb = 0.f, yc2 = 0.f, yd = 0.f;
#pragma unroll
      for (int s = 0; s < 4; ++s) {
        float dA = __expf(dlv * Aval[s]);
        h[s] = dA * h[s] + w * Bv[0][s];
        ya += h[s] * Cv[0][s];
      }
#pragma unroll
      for (int s = 4; s < 8; ++s) {
        float dA = __expf(dlv * Aval[s]);
        h[s] = dA * h[s] + w * Bv[1][s - 4];
        yb += h[s] * Cv[1][s - 4];
      }
#pragma unroll
      for (int s = 8; s < 12; ++s) {
        float dA = __expf(dlv * Aval[s]);
        h[s] = dA * h[s] + w * Bv[2][s - 8];
        yc2 += h[s] * Cv[2][s - 8];
      }
#pragma unroll
      for (int s = 12; s < 16; ++s) {
        float dA = __expf(dlv * Aval[s]);
        h[s] = dA * h[s] + w * Bv[3][s - 12];
        yd += h[s] * Cv[3][s - 12];
      }
      float yv = (ya + yb) + (yc2 + yd);
      float yf = (yv + xv * Dval) * z1;
      u16 hh = f2bf_rn(yf);
      yh[off] = hh;
      yl[off] = f2bf_rn(yf - bf2f(hh));
    }
  }
}

extern "C" void kernel_launch(void* const* d_in, const int* in_sizes, int n_in, void* d_out,
                              int out_size, void* d_ws, size_t ws_size, hipStream_t stream) {
  const float* input = (const float*)d_in[0];
  const float* in_proj_w = (const float*)d_in[1];
  const float* conv_w = (const float*)d_in[2];
  const float* conv_b = (const float*)d_in[3];
  const float* x_proj_w = (const float*)d_in[4];
  const float* dt_proj_w = (const float*)d_in[5];
  const float* dt_proj_b = (const float*)d_in[6];
  const float* A_log = (const float*)d_in[7];
  const float* Dp = (const float*)d_in[8];
  const float* out_proj_w = (const float*)d_in[9];
  const float* out_lin_w = (const float*)d_in[10];
  const float* out_lin_b = (const float*)d_in[11];

  char* ws = (char*)d_ws;
  u16* buf_xh = (u16*)(ws);                  // 8.39 MB
  u16* buf_xl = (u16*)(ws + 8388608);        // 8.39 MB
  float* buf_xr = (float*)(ws + 16777216);   // 33.55 MB fp32 xr (Hl/sd alias after conv; then y)
  float* buf_zs = (float*)(ws + 50331648);   // 33.55 MB fp32 silu(z)
  u16* buf_xch = (u16*)(ws + 83886080);      // 16 MB
  u16* buf_xcl = (u16*)(ws + 100663296);     // 16 MB
  float* buf_bc = (float*)(ws + 117440512);  // 2 MB (M_ROWS x 32)
  u16* buf_wch = (u16*)(ws + 119537664);     // 0.5 MB
  u16* buf_wcl = (u16*)(ws + 120061952);     // 0.5 MB
  float* buf_d = (float*)(ws + 120586240);   // 33.55 MB fp32 delta
  u16* buf_wd0h = (u16*)(ws + 154140672);    // 640x512 planes (576 live + 64 zero-pad rows)
  u16* buf_wd0l = (u16*)(ws + 154796032);
  u16* buf_wd1h = (u16*)(ws + 155451392);
  u16* buf_wd1l = (u16*)(ws + 156106752);
  u16* buf_wth = (u16*)(ws + 156762112);     // 0.5 MB reusable weight scratch
  u16* buf_wtl = (u16*)(ws + 157286400);
  float* buf_Hl = (float*)(ws + 16777216);   // 8.39 MB (xr dead after conv)
  float* buf_sd = (float*)(ws + 25165824);   // 0.52 MB (B x NC x 512)
  float* buf_H0 = (float*)ws;                // 8.39 MB (x planes dead during scan)
  u16* buf_yh = (u16*)(ws + 16777216);       // over Hl (dead after combine)
  u16* buf_yl = (u16*)(ws + 33554432);       // free region during scan

  build_wd<<<dim3(2, 640), 256, 0, stream>>>(x_proj_w, dt_proj_w, buf_wd0h, buf_wd0l);
  build_wd<<<dim3(2, 640), 256, 0, stream>>>(x_proj_w + 48 * 512, dt_proj_w + 512 * 16, buf_wd1h,
                                             buf_wd1l);
  build_wcomb<<<dim3(2, 512), 256, 0, stream>>>(out_lin_w, out_proj_w + (long)256 * 512, buf_wch,
                                                buf_wcl);
  transpose_in<<<dim3(64, 8, 8), dim3(32, 8), 0, stream>>>(input, buf_xh, buf_xl);

  for (int i = 0; i < 2; ++i) {
    split_pack<<<1024, 256, 0, stream>>>(in_proj_w + (long)i * 1024 * 256, buf_wth, buf_wtl,
                                         1024 * 256);
    gemm_mfma<3, 8, 2><<<1024, 512, 0, stream>>>(buf_xh, buf_xl, 256, buf_wth, buf_wtl, 256,
                                                 nullptr, nullptr, buf_xr, buf_zs, nullptr,
                                                 nullptr, nullptr);
    conv_silu<<<512, 256, 0, stream>>>(buf_xr, conv_w + i * 512 * 4, conv_b + i * 512,
                                       buf_xch, buf_xcl);
    gemm_mfma<4, 5, 2><<<640, 512, 0, stream>>>(
        buf_xch, buf_xcl, 512, (i == 0) ? buf_wd0h : buf_wd1h, (i == 0) ? buf_wd0l : buf_wd1l,
        512, nullptr, buf_bc, buf_d, nullptr, nullptr, nullptr, dt_proj_b + i * 512);
    scan_pass1<<<dim3(2, NC, 8), 256, 0, stream>>>(buf_d, buf_xch, buf_xcl, buf_bc,
                                                   A_log + (long)i * 512 * 16, buf_sd, buf_Hl);
    scan_combine<<<256, 256, 0, stream>>>(A_log + (long)i * 512 * 16, buf_sd, buf_Hl, buf_H0);
    scan_pass2<<<dim3(2, NC, 8), 256, 0, stream>>>(buf_d, buf_yh, buf_yl, buf_xch, buf_xcl,
                                                   buf_bc, buf_zs,
                                                   A_log + (long)i * 512 * 16, Dp + i * 512,
                                                   buf_H0);
    if (i == 0) {
      split_pack<<<512, 256, 0, stream>>>(out_proj_w, buf_wth, buf_wtl, 256 * 512);
      gemm_mfma<5, 4, 1><<<1024, 256, 0, stream>>>(buf_yh, buf_yl, 512, buf_wth, buf_wtl, 512,
                                                   nullptr, nullptr, nullptr, nullptr, buf_xh,
                                                   buf_xl, nullptr);
    } else {
      gemm_mfma<2, 8, 1><<<2048, 256, 0, stream>>>(buf_yh, buf_yl, 512, buf_wch, buf_wcl, 512,
                                                   (float*)d_out, nullptr, nullptr, nullptr,
                                                   nullptr, nullptr, out_lin_b);
    }
  }
}